// Round 11
// baseline (222.760 us; speedup 1.0000x reference)
//
#include <hip/hip_runtime.h>
#include <stdint.h>

#define A_N 9
#define H_N 50
#define W_N 76
#define HW_N (H_N * W_N)      // 3800
#define N_PROP (A_N * HW_N)   // 34200
#define B_N 4
#define PRE_NMS 4000
#define POST_NMS 300
#define NMS_TH 0.7f
#define SORT_N 4096
#define MASK_WORDS 64
#define CAND_MAX 5120
#define NBINS 4096
#define NPAIR 32
#define NLW 5
#define DEC_BLKS ((N_PROP + 255) / 256)   // 134

// ---------------------------------------------------------------------------
// Kernel A: decode + keys, WIDE grid (r10 lesson: 4-block fused front was
// latency-bound on 4 CUs, 55us; r8's wide decode was ~8us). No histogram
// here at all — mid_kernel rebuilds it from keys (same multiset, bit-exact).
// ---------------------------------------------------------------------------
__global__ __launch_bounds__(256) void decode_kernel(
    const float* __restrict__ scores,
    const float* __restrict__ deltas,
    const float* __restrict__ im_info,
    const float* __restrict__ anchors,
    float4* __restrict__ boxes,
    unsigned long long* __restrict__ keys) {
#pragma clang fp contract(off)
    int tid = threadIdx.x;
    int b = blockIdx.y;
    int r = blockIdx.x * 256 + tid;
    if (r >= N_PROP) return;

    int a = r / HW_N;          // fixed across a wave
    int hw = r - a * HW_N;     // consecutive across lanes
    int hy = hw / W_N;
    int wx = hw - hy * W_N;

    float sx = (float)wx * 16.0f;
    float sy = (float)hy * 16.0f;
    float ax1 = anchors[a * 4 + 0] + sx;
    float ay1 = anchors[a * 4 + 1] + sy;
    float ax2 = anchors[a * 4 + 2] + sx;
    float ay2 = anchors[a * 4 + 3] + sy;
    float aw = ax2 - ax1 + 1.0f;
    float ah = ay2 - ay1 + 1.0f;
    float cx = ax1 + 0.5f * aw;
    float cy = ay1 + 0.5f * ah;

    const float* db = deltas + ((size_t)b * 36 + (size_t)a * 4) * HW_N + hw;
    float d0 = db[0];
    float d1 = db[HW_N];
    float d2 = db[2 * HW_N];
    float d3 = db[3 * HW_N];

    float pcx = d0 * aw + cx;
    float pcy = d1 * ah + cy;
    float pw  = expf(d2) * aw;
    float ph  = expf(d3) * ah;

    float x1 = pcx - 0.5f * pw;
    float y1 = pcy - 0.5f * ph;
    float x2 = pcx + 0.5f * pw;
    float y2 = pcy + 0.5f * ph;

    float xhi = im_info[b * 3 + 1] - 1.0f;
    float yhi = im_info[b * 3 + 0] - 1.0f;
    x1 = fminf(fmaxf(x1, 0.0f), xhi);
    y1 = fminf(fmaxf(y1, 0.0f), yhi);
    x2 = fminf(fmaxf(x2, 0.0f), xhi);
    y2 = fminf(fmaxf(y2, 0.0f), yhi);

    boxes[(size_t)b * N_PROP + r] = make_float4(x1, y1, x2, y2);  // a-major

    float s = scores[((size_t)b * A_N + a) * HW_N + hw];
    unsigned f = __float_as_uint(s);
    unsigned sk = f ^ ((f & 0x80000000u) ? 0xFFFFFFFFu : 0x80000000u);
    unsigned n_ref = (unsigned)(hw * A_N + a);
    unsigned long long key = ((unsigned long long)sk << 32) | (unsigned)(~n_ref);
    keys[(size_t)b * N_PROP + r] = key;
}

// ---------------------------------------------------------------------------
// Kernel B' (mid): LDS histogram from keys + findT + compact, one block per
// batch (only __syncthreads; no global ghist, no memset). Keys are L2-hot
// from decode. Logic verbatim from r10 front (which passed) minus decode.
// ---------------------------------------------------------------------------
__global__ __launch_bounds__(1024) void mid_kernel(
    const unsigned long long* __restrict__ keys,
    unsigned* __restrict__ cnt,
    unsigned long long* __restrict__ cand) {
    __shared__ unsigned hist[NBINS];
    __shared__ int Tlds;
    __shared__ unsigned cntL;
    const int b = blockIdx.x;
    const int tid = threadIdx.x;

    for (int i = tid; i < NBINS; i += 1024) hist[i] = 0u;
    if (tid == 0) cntL = 0u;
    __syncthreads();

    for (int it = 0; it < (N_PROP + 1023) / 1024; ++it) {
        int n = it * 1024 + tid;
        if (n < N_PROP) {
            unsigned long long k = keys[(size_t)b * N_PROP + n];
            atomicAdd(&hist[(unsigned)(k >> 52)], 1u);
        }
    }
    __syncthreads();

    // ---- findT (wave 0; verbatim) ----
    if (tid < 64) {
        int lane = tid;
        unsigned gsum = 0;
        for (int j = 0; j < 64; ++j) gsum += hist[lane * 64 + j];
        unsigned s = gsum;
        for (int d = 1; d < 64; d <<= 1) {
            unsigned t = (unsigned)__shfl_down((int)s, d);
            if (lane + d < 64) s += t;
        }
        unsigned long long bal = __ballot(s >= PRE_NMS);
        int gstar = 63 - __builtin_clzll(bal);
        unsigned after = (gstar < 63)
            ? (unsigned)__builtin_amdgcn_readlane((int)s, gstar + 1) : 0u;
        unsigned R = PRE_NMS - after;
        unsigned s2 = hist[gstar * 64 + lane];
        for (int d = 1; d < 64; d <<= 1) {
            unsigned t = (unsigned)__shfl_down((int)s2, d);
            if (lane + d < 64) s2 += t;
        }
        unsigned long long bal2 = __ballot(s2 >= R);
        int j = 63 - __builtin_clzll(bal2);
        if (lane == 0) Tlds = gstar * 64 + j;
    }
    __syncthreads();

    // ---- compact (wave-aggregated LDS atomic) ----
    const int Tb = Tlds;
    for (int it = 0; it < (N_PROP + 1023) / 1024; ++it) {
        int n = it * 1024 + tid;
        bool pred = false;
        unsigned long long k = 0ull;
        if (n < N_PROP) {
            k = keys[(size_t)b * N_PROP + n];
            pred = ((int)(unsigned)(k >> 52) >= Tb);
        }
        unsigned long long m = __ballot(pred);
        if (m) {
            int lane = tid & 63;
            int lead = __ffsll((unsigned long long)m) - 1;
            unsigned base = 0;
            if (lane == lead) base = atomicAdd(&cntL, (unsigned)__popcll(m));
            base = __shfl((int)base, lead);
            if (pred) {
                unsigned pos = base + (unsigned)__popcll(m & ((1ull << lane) - 1ull));
                if (pos < CAND_MAX) cand[(size_t)b * CAND_MAX + pos] = k;
            }
        }
    }
    __syncthreads();
    if (tid == 0) cnt[b] = cntL;
}

// ---------------------------------------------------------------------------
// Kernel D: exact rank by pairwise count (unchanged from r8).
// ---------------------------------------------------------------------------
__global__ __launch_bounds__(256) void rank_scatter_kernel(
    const unsigned long long* __restrict__ cand,
    const unsigned* __restrict__ cnt,
    const float4* __restrict__ boxes,
    float4* __restrict__ sortedBoxes) {
    __shared__ unsigned long long sk[256];
    int b = blockIdx.y;
    int tid = threadIdx.x;
    int ci = blockIdx.x * 64 + (tid >> 2);
    int q = tid & 3;
    int mc = (int)min(cnt[b], (unsigned)CAND_MAX);
    unsigned long long my = (ci < mc) ? cand[(size_t)b * CAND_MAX + ci] : 0ull;
    int rank = 0;
    int nt = (mc + 255) >> 8;
    for (int t = 0; t < nt; ++t) {
        int j = t * 256 + tid;
        sk[tid] = (j < mc) ? cand[(size_t)b * CAND_MAX + j] : 0ull;
        __syncthreads();
#pragma unroll 16
        for (int c = 0; c < 64; ++c) {
            int cc = q * 64 + ((c + q * 17) & 63);  // stagger: avoid 4-way bank conflict
            rank += (sk[cc] > my) ? 1 : 0;
        }
        __syncthreads();
    }
    rank += __shfl_xor(rank, 1);
    rank += __shfl_xor(rank, 2);
    if (q == 0 && ci < mc && rank < PRE_NMS) {
        unsigned n_ref = ~(unsigned)(my & 0xFFFFFFFFull);
        unsigned a = n_ref % A_N;
        unsigned hw = n_ref / A_N;
        sortedBoxes[(size_t)b * SORT_N + rank] =
            boxes[(size_t)b * N_PROP + a * HW_N + hw];
    }
    if (q == 1) {
        int pi = blockIdx.x * 64 + (tid >> 2);
        if (pi >= PRE_NMS && pi < SORT_N)
            sortedBoxes[(size_t)b * SORT_N + pi] = make_float4(0.f, 0.f, 0.f, 0.f);
    }
}

// ---------------------------------------------------------------------------
// Kernel E: suppression bitmask, upper-triangle-only grid (unchanged from r8)
// ---------------------------------------------------------------------------
__global__ __launch_bounds__(256) void iou_mask_kernel(
    const float4* __restrict__ sortedBoxes,
    unsigned long long* __restrict__ colmaj,
    unsigned long long* __restrict__ rowmaj) {
#pragma clang fp contract(off)
    int b = blockIdx.y;
    int wv = threadIdx.x >> 6;
    int t = threadIdx.x & 63;
    int k = blockIdx.x * 4 + wv;          // 0..2079, upper-tri linear index
    int rc = 0;
    while (k >= 64 - rc) { k -= 64 - rc; ++rc; }
    int cc = rc + k;

    __shared__ float4 colb[4][64];
    colb[wv][t] = sortedBoxes[(size_t)b * SORT_N + cc * 64 + t];
    __syncthreads();

    int r = rc * 64 + t;
    float4 rb = sortedBoxes[(size_t)b * SORT_N + r];
    float rarea = (rb.z - rb.x) * (rb.w - rb.y);
    unsigned long long word = 0ull;
    for (int c = 0; c < 64; ++c) {
        int j = cc * 64 + c;
        float4 cb = colb[wv][c];
        float carea = (cb.z - cb.x) * (cb.w - cb.y);
        float ltx = fmaxf(rb.x, cb.x);
        float lty = fmaxf(rb.y, cb.y);
        float rbx = fminf(rb.z, cb.z);
        float rby = fminf(rb.w, cb.w);
        float iw = fmaxf(rbx - ltx, 0.0f);
        float ih = fmaxf(rby - lty, 0.0f);
        float inter = iw * ih;
        float iou = inter / (rarea + carea - inter + 1e-9f);
        if (iou > NMS_TH && j > r) word |= (1ull << c);
    }
    colmaj[((size_t)b * MASK_WORDS + cc) * SORT_N + r] = word;   // coalesced
    rowmaj[((size_t)b * SORT_N + r) * MASK_WORDS + cc] = word;   // scatter
}

// ---------------------------------------------------------------------------
// Kernel F: MULTI-WAVE greedy scan, RAW-BARRIER PIPELINED.
// r10 diagnosis: redor64 = serial chain of 6 dependent __shfl_xor
// (ds_bpermute ~60+cy each, x2 for 64-bit) ~= 700cy per reduction; decider
// ran 5/iter -> ~48us of the measured 53.5. alive masks are sparse
// (~9.4 kept/pair) -> per-kept readlane accumulation (~6 readlanes/kept,
// pipelined) replaces ALL redor64 uses in decider and helper.
// ---------------------------------------------------------------------------
__device__ __forceinline__ unsigned long long rl64(unsigned long long v, int src) {
    unsigned lo = (unsigned)__builtin_amdgcn_readlane((int)(unsigned)(v & 0xFFFFFFFFull), src);
    unsigned hi = (unsigned)__builtin_amdgcn_readlane((int)(unsigned)(v >> 32), src);
    return ((unsigned long long)hi << 32) | lo;
}

__device__ __forceinline__ void block_sync() {
    asm volatile("s_waitcnt lgkmcnt(0)" ::: "memory");   // LDS visibility, NO vmcnt drain
    __builtin_amdgcn_s_barrier();
    asm volatile("" ::: "memory");
}

#define GLOAD(dst, addr) \
    asm volatile("global_load_dwordx2 %0, %1, off" : "=v"(dst) : "v"(addr))
#define WAITV0 asm volatile("s_waitcnt vmcnt(0)" ::: "memory")
#define SCHED0 __builtin_amdgcn_sched_barrier(0)

#define TILE_COL(P, t) ((t) < 6 ? 2 * (P) + (t) : 2 * (P) + 1 + ((t) - 6))
#define TILE_RB(P, t)  ((size_t)((t) < 6 ? 2 * (P) : 2 * (P) + 1) << 6)
#define TILE_ADDR(P, t) \
    (C + (size_t)(TILE_COL(P, t) < 64 ? TILE_COL(P, t) : 63) * SORT_N + TILE_RB(P, t) + lane)

#define ISSUE_PAIR(P)                                                          \
    do {                                                                       \
        pf_vmask = 0u;                                                         \
        GLOAD(pf0,  TILE_ADDR(P, 0));  if (TILE_COL(P, 0)  < 64) pf_vmask |= 1u << 0;  \
        GLOAD(pf1,  TILE_ADDR(P, 1));  if (TILE_COL(P, 1)  < 64) pf_vmask |= 1u << 1;  \
        GLOAD(pf2,  TILE_ADDR(P, 2));  if (TILE_COL(P, 2)  < 64) pf_vmask |= 1u << 2;  \
        GLOAD(pf3,  TILE_ADDR(P, 3));  if (TILE_COL(P, 3)  < 64) pf_vmask |= 1u << 3;  \
        GLOAD(pf4,  TILE_ADDR(P, 4));  if (TILE_COL(P, 4)  < 64) pf_vmask |= 1u << 4;  \
        GLOAD(pf5,  TILE_ADDR(P, 5));  if (TILE_COL(P, 5)  < 64) pf_vmask |= 1u << 5;  \
        GLOAD(pf6,  TILE_ADDR(P, 6));  if (TILE_COL(P, 6)  < 64) pf_vmask |= 1u << 6;  \
        GLOAD(pf7,  TILE_ADDR(P, 7));  if (TILE_COL(P, 7)  < 64) pf_vmask |= 1u << 7;  \
        GLOAD(pf8,  TILE_ADDR(P, 8));  if (TILE_COL(P, 8)  < 64) pf_vmask |= 1u << 8;  \
        GLOAD(pf9,  TILE_ADDR(P, 9));  if (TILE_COL(P, 9)  < 64) pf_vmask |= 1u << 9;  \
        GLOAD(pf10, TILE_ADDR(P, 10)); if (TILE_COL(P, 10) < 64) pf_vmask |= 1u << 10; \
    } while (0)

#define NEXTROW2(rk)                                                           \
    int rk;                                                                    \
    {                                                                          \
        if (xA) { int bb_ = __builtin_ctzll(xA); xA &= xA - 1; rk = baseA + bb_; } \
        else if (xB) { int bb_ = __builtin_ctzll(xB); xB &= xB - 1; rk = baseB + bb_; } \
        else rk = rpad;                                                        \
    }

__global__ __launch_bounds__(512, 1) void nms_scan_kernel(
    const unsigned long long* __restrict__ colmaj,
    const unsigned long long* __restrict__ rowmaj,
    const float4* __restrict__ sortedBoxes,
    float* __restrict__ out) {
    int b = blockIdx.x;
    int tid = threadIdx.x;
    int lane = tid & 63;
    int wv = tid >> 6;   // 0 decider, 1 prefetch, 2 helper, 3..7 loaders
    const unsigned long long* C = colmaj + (size_t)b * MASK_WORDS * SORT_N;
    const unsigned long long* R = rowmaj + (size_t)b * SORT_N * MASK_WORDS;

    __shared__ int kept[POST_NMS];
    __shared__ unsigned remW[MASK_WORDS][2];            // [word][lo,hi]
    __shared__ unsigned long long aliveLds[MASK_WORDS];
    __shared__ unsigned long long ring[4][11][64];      // tile ring, slot = pair&3
    __shared__ unsigned long long car2[2][2];           // helper d2 carries, slot = pair&1
    __shared__ int doneLds;
    __shared__ int kcntLds;

    if (tid < MASK_WORDS) { remW[tid][0] = 0u; remW[tid][1] = 0u; aliveLds[tid] = 0ull; }
    if (tid < 4) car2[tid >> 1][tid & 1] = 0ull;
    if (tid == 0) { doneLds = 0; kcntLds = 0; }

    unsigned long long pf0=0,pf1=0,pf2=0,pf3=0,pf4=0,pf5=0,pf6=0,pf7=0,pf8=0,pf9=0,pf10=0;
    unsigned pf_vmask = 0u;
    bool pf_have = false;
    unsigned long long gp0=0,gp1=0,gp2=0,gp3=0,gp4=0,gp5=0,gp6=0,gp7=0;
    bool ld_valid = false;

    // ---- prologue: stage pair 0 synchronously, issue pair 1 (in flight) ----
    if (wv == 1) {
        for (int t = 0; t < 11; ++t) {
            int col = TILE_COL(0, t);
            unsigned long long v =
                (col < 64) ? C[(size_t)col * SORT_N + TILE_RB(0, t) + lane] : 0ull;
            ring[0][t][lane] = v;
        }
        ISSUE_PAIR(1);
        pf_have = true;
    }
    block_sync();

    unsigned long long carA = 0ull, carB = 0ull;   // decider: d1 carries (pair q-1 -> q)
    int kcnt = 0;

    for (int q = 0; q < NPAIR; ++q) {
        if (wv == 0) {
            // ---------------- decider: pair q ----------------
            int A = 2 * q, Bg = A + 1, slot = q & 3;
            unsigned long long dA  = ring[slot][0][lane];
            unsigned long long tA1 = ring[slot][1][lane];
            unsigned long long tA2 = ring[slot][2][lane];
            unsigned long long tA3 = ring[slot][3][lane];
            unsigned long long dB  = ring[slot][6][lane];
            unsigned long long tB1 = ring[slot][7][lane];
            unsigned long long tB2 = ring[slot][8][lane];
            unsigned long long remA =
                ((unsigned long long)remW[A][1] << 32) | (unsigned long long)remW[A][0];
            unsigned long long remB =
                ((unsigned long long)remW[Bg][1] << 32) | (unsigned long long)remW[Bg][0];
            unsigned long long h2A = car2[q & 1][0];
            unsigned long long h2B = car2[q & 1][1];
            bool hit = false;
            unsigned long long aliveA = 0ull, aliveB = 0ull;
            unsigned long long pend = ~(remA | carA | h2A);
            while (pend) {
                int bit = __builtin_ctzll(pend);
                if (lane == 0) kept[kcnt] = (A << 6) + bit;
                ++kcnt;
                aliveA |= 1ull << bit;
                if (kcnt == POST_NMS) { hit = true; break; }
                pend &= ~(rl64(dA, bit) | (1ull << bit));
            }
            unsigned long long ncA = 0ull, ncB = 0ull;
            if (!hit) {
                // per-kept readlane accumulation (alive is sparse; replaces
                // the 6-deep dependent shfl_xor chains that were ~48us total)
                unsigned long long nA1 = 0ull;
                unsigned long long am = aliveA;
                while (am) {
                    int i = __builtin_ctzll(am); am &= am - 1;
                    nA1 |= rl64(tA1, i);
                    ncA |= rl64(tA2, i);
                    ncB |= rl64(tA3, i);
                }
                pend = ~(remB | carB | h2B | nA1);
                while (pend) {
                    int bit = __builtin_ctzll(pend);
                    if (lane == 0) kept[kcnt] = (Bg << 6) + bit;
                    ++kcnt;
                    aliveB |= 1ull << bit;
                    if (kcnt == POST_NMS) { hit = true; break; }
                    pend &= ~(rl64(dB, bit) | (1ull << bit));
                }
                am = aliveB;
                while (am) {
                    int i = __builtin_ctzll(am); am &= am - 1;
                    ncA |= rl64(tB1, i);
                    ncB |= rl64(tB2, i);
                }
            }
            carA = ncA;
            carB = ncB;
            if (lane == 0) {
                aliveLds[A]  = aliveA;
                aliveLds[Bg] = aliveB;
                kcntLds = kcnt;
                if (hit) doneLds = 1;
            }
        } else if (wv == 1) {
            // ---------------- prefetch: write pair q+1, issue pair q+2 ------
            if (pf_have) {
                WAITV0;
                SCHED0;
                int wp = q + 1;
                if (wp < NPAIR) {
                    int ws = wp & 3;
                    ring[ws][0][lane]  = (pf_vmask & (1u << 0))  ? pf0  : 0ull;
                    ring[ws][1][lane]  = (pf_vmask & (1u << 1))  ? pf1  : 0ull;
                    ring[ws][2][lane]  = (pf_vmask & (1u << 2))  ? pf2  : 0ull;
                    ring[ws][3][lane]  = (pf_vmask & (1u << 3))  ? pf3  : 0ull;
                    ring[ws][4][lane]  = (pf_vmask & (1u << 4))  ? pf4  : 0ull;
                    ring[ws][5][lane]  = (pf_vmask & (1u << 5))  ? pf5  : 0ull;
                    ring[ws][6][lane]  = (pf_vmask & (1u << 6))  ? pf6  : 0ull;
                    ring[ws][7][lane]  = (pf_vmask & (1u << 7))  ? pf7  : 0ull;
                    ring[ws][8][lane]  = (pf_vmask & (1u << 8))  ? pf8  : 0ull;
                    ring[ws][9][lane]  = (pf_vmask & (1u << 9))  ? pf9  : 0ull;
                    ring[ws][10][lane] = (pf_vmask & (1u << 10)) ? pf10 : 0ull;
                }
                pf_have = false;
            }
            int ip = q + 2;
            if (ip < NPAIR) {
                ISSUE_PAIR(ip);
                pf_have = true;
            }
        } else if (wv == 2) {
            // ---------------- helper: pair p=q-1 d2 carries -> pair q+1 -----
            if (q >= 1) {
                int p = q - 1, sp = p & 3;
                unsigned long long aA = aliveLds[2 * p];
                unsigned long long aB = aliveLds[2 * p + 1];
                unsigned long long tA4 = ring[sp][4][lane];
                unsigned long long tA5 = ring[sp][5][lane];
                unsigned long long tB3 = ring[sp][9][lane];
                unsigned long long tB4 = ring[sp][10][lane];
                unsigned long long c0 = 0ull, c1 = 0ull;
                unsigned long long am = aA;
                while (am) {
                    int i = __builtin_ctzll(am); am &= am - 1;
                    c0 |= rl64(tA4, i);
                    c1 |= rl64(tA5, i);
                }
                am = aB;
                while (am) {
                    int i = __builtin_ctzll(am); am &= am - 1;
                    c0 |= rl64(tB3, i);
                    c1 |= rl64(tB4, i);
                }
                if (lane == 0) {
                    car2[(q + 1) & 1][0] = c0;
                    car2[(q + 1) & 1][1] = c1;
                }
            }
        } else {
            // ---------------- loaders: fold prev batch, issue pair q-1 ------
            if (ld_valid) {
                WAITV0;
                SCHED0;
                unsigned long long acc =
                    ((gp0 | gp1) | (gp2 | gp3)) | ((gp4 | gp5) | (gp6 | gp7));
                unsigned lo = (unsigned)acc, hi = (unsigned)(acc >> 32);
                if (lo) atomicOr(&remW[lane][0], lo);
                if (hi) atomicOr(&remW[lane][1], hi);
                ld_valid = false;
            }
            if (q >= 1) {
                int p = q - 1, gA = 2 * p, gB = 2 * p + 1;
                unsigned long long aA = aliveLds[gA];
                unsigned long long aB = aliveLds[gB];
                int k = wv - 3;                       // 0..NLW-1
                unsigned long long below = (1ull << lane) - 1ull;
                bool inA = (aA >> lane) & 1ull;
                bool inB = (aB >> lane) & 1ull;
                int posA = (int)__popcll(aA & below);
                int posB = (int)__popcll(aA) + (int)__popcll(aB & below);
                unsigned long long mA = __ballot(inA && (posA % NLW) == k);
                unsigned long long mB = __ballot(inB && (posB % NLW) == k);
                if (mA | mB) {
                    int baseA = gA << 6, baseB = gB << 6;
                    unsigned long long xA = mA, xB = mB;
                    int rpad = mA ? (baseA + __builtin_ctzll(mA))
                                  : (baseB + __builtin_ctzll(mB));
                    NEXTROW2(r0) NEXTROW2(r1) NEXTROW2(r2) NEXTROW2(r3)
                    NEXTROW2(r4) NEXTROW2(r5) NEXTROW2(r6) NEXTROW2(r7)
                    const unsigned long long* Rb = R + lane;
                    GLOAD(gp0, Rb + (size_t)r0 * MASK_WORDS);
                    GLOAD(gp1, Rb + (size_t)r1 * MASK_WORDS);
                    GLOAD(gp2, Rb + (size_t)r2 * MASK_WORDS);
                    GLOAD(gp3, Rb + (size_t)r3 * MASK_WORDS);
                    GLOAD(gp4, Rb + (size_t)r4 * MASK_WORDS);
                    GLOAD(gp5, Rb + (size_t)r5 * MASK_WORDS);
                    GLOAD(gp6, Rb + (size_t)r6 * MASK_WORDS);
                    GLOAD(gp7, Rb + (size_t)r7 * MASK_WORDS);
                    ld_valid = true;
                    // overflow rows (>8 for this wave): rare, serial
                    unsigned long long ovf = 0ull;
                    while (xA) {
                        int bb = __builtin_ctzll(xA); xA &= xA - 1;
                        ovf |= Rb[(size_t)(baseA + bb) * MASK_WORDS];
                    }
                    while (xB) {
                        int bb = __builtin_ctzll(xB); xB &= xB - 1;
                        ovf |= Rb[(size_t)(baseB + bb) * MASK_WORDS];
                    }
                    if (ovf) {
                        unsigned lo = (unsigned)ovf, hi = (unsigned)(ovf >> 32);
                        if (lo) atomicOr(&remW[lane][0], lo);
                        if (hi) atomicOr(&remW[lane][1], hi);
                    }
                }
            }
        }
        block_sync();
        if (doneLds) break;
    }

    WAITV0;             // drain any in-flight asm loads before ending
    __syncthreads();

    int kc = kcntLds;   // last write barrier-ordered before every exit path
    for (int r = tid; r < POST_NMS; r += 512) {
        float* o = out + ((size_t)b * POST_NMS + r) * 5;
        float4 bx = make_float4(0.f, 0.f, 0.f, 0.f);
        if (r < kc) bx = sortedBoxes[(size_t)b * SORT_N + kept[r]];
        o[0] = (float)b;
        o[1] = bx.x;
        o[2] = bx.y;
        o[3] = bx.z;
        o[4] = bx.w;
    }
}

// ---------------------------------------------------------------------------
extern "C" void kernel_launch(void* const* d_in, const int* in_sizes, int n_in,
                              void* d_out, int out_size, void* d_ws, size_t ws_size,
                              hipStream_t stream) {
    const float* scores  = (const float*)d_in[0];
    const float* deltas  = (const float*)d_in[1];
    const float* im_info = (const float*)d_in[2];
    const float* anchors = (const float*)d_in[3];
    float* out = (float*)d_out;

    char* ws = (char*)d_ws;
    size_t off = 0;
    float4* boxes = (float4*)(ws + off);
    off += (size_t)B_N * N_PROP * sizeof(float4);
    off = (off + 255) & ~(size_t)255;
    unsigned long long* keys = (unsigned long long*)(ws + off);
    off += (size_t)B_N * N_PROP * sizeof(unsigned long long);
    off = (off + 255) & ~(size_t)255;
    float4* sortedBoxes = (float4*)(ws + off);
    off += (size_t)B_N * SORT_N * sizeof(float4);
    off = (off + 255) & ~(size_t)255;
    unsigned long long* colmaj = (unsigned long long*)(ws + off);
    off += (size_t)B_N * MASK_WORDS * SORT_N * sizeof(unsigned long long);
    off = (off + 255) & ~(size_t)255;
    unsigned long long* rowmaj = (unsigned long long*)(ws + off);
    off += (size_t)B_N * SORT_N * MASK_WORDS * sizeof(unsigned long long);
    off = (off + 255) & ~(size_t)255;
    unsigned long long* cand = (unsigned long long*)(ws + off);
    off += (size_t)B_N * CAND_MAX * sizeof(unsigned long long);
    off = (off + 255) & ~(size_t)255;
    unsigned* cnt = (unsigned*)(ws + off);
    off += (size_t)B_N * sizeof(unsigned);

    decode_kernel<<<dim3(DEC_BLKS, B_N), 256, 0, stream>>>(
        scores, deltas, im_info, anchors, boxes, keys);
    mid_kernel<<<B_N, 1024, 0, stream>>>(keys, cnt, cand);
    rank_scatter_kernel<<<dim3(CAND_MAX / 64, B_N), 256, 0, stream>>>(
        cand, cnt, boxes, sortedBoxes);
    iou_mask_kernel<<<dim3(520, B_N), 256, 0, stream>>>(sortedBoxes, colmaj, rowmaj);
    nms_scan_kernel<<<B_N, 512, 0, stream>>>(colmaj, rowmaj, sortedBoxes, out);
}

// Round 12
// 203.540 us; speedup vs baseline: 1.0944x; 1.0944x over previous
//
#include <hip/hip_runtime.h>
#include <stdint.h>

#define A_N 9
#define H_N 50
#define W_N 76
#define HW_N (H_N * W_N)      // 3800
#define N_PROP (A_N * HW_N)   // 34200
#define B_N 4
#define PRE_NMS 4000
#define POST_NMS 300
#define NMS_TH 0.7f
#define SORT_N 4096
#define MASK_WORDS 64
#define CAND_MAX 5120
#define NBINS 4096
#define NPAIR 32
#define NLW 5
#define DEC_BLKS ((N_PROP + 255) / 256)   // 134

// ---------------------------------------------------------------------------
// Kernel A: decode + keys, WIDE grid (r10: narrow fused front was
// latency-bound on 4 CUs). No histogram — mid_kernel rebuilds from keys.
// ---------------------------------------------------------------------------
__global__ __launch_bounds__(256) void decode_kernel(
    const float* __restrict__ scores,
    const float* __restrict__ deltas,
    const float* __restrict__ im_info,
    const float* __restrict__ anchors,
    float4* __restrict__ boxes,
    unsigned long long* __restrict__ keys) {
#pragma clang fp contract(off)
    int tid = threadIdx.x;
    int b = blockIdx.y;
    int r = blockIdx.x * 256 + tid;
    if (r >= N_PROP) return;

    int a = r / HW_N;          // fixed across a wave
    int hw = r - a * HW_N;     // consecutive across lanes
    int hy = hw / W_N;
    int wx = hw - hy * W_N;

    float sx = (float)wx * 16.0f;
    float sy = (float)hy * 16.0f;
    float ax1 = anchors[a * 4 + 0] + sx;
    float ay1 = anchors[a * 4 + 1] + sy;
    float ax2 = anchors[a * 4 + 2] + sx;
    float ay2 = anchors[a * 4 + 3] + sy;
    float aw = ax2 - ax1 + 1.0f;
    float ah = ay2 - ay1 + 1.0f;
    float cx = ax1 + 0.5f * aw;
    float cy = ay1 + 0.5f * ah;

    const float* db = deltas + ((size_t)b * 36 + (size_t)a * 4) * HW_N + hw;
    float d0 = db[0];
    float d1 = db[HW_N];
    float d2 = db[2 * HW_N];
    float d3 = db[3 * HW_N];

    float pcx = d0 * aw + cx;
    float pcy = d1 * ah + cy;
    float pw  = expf(d2) * aw;
    float ph  = expf(d3) * ah;

    float x1 = pcx - 0.5f * pw;
    float y1 = pcy - 0.5f * ph;
    float x2 = pcx + 0.5f * pw;
    float y2 = pcy + 0.5f * ph;

    float xhi = im_info[b * 3 + 1] - 1.0f;
    float yhi = im_info[b * 3 + 0] - 1.0f;
    x1 = fminf(fmaxf(x1, 0.0f), xhi);
    y1 = fminf(fmaxf(y1, 0.0f), yhi);
    x2 = fminf(fmaxf(x2, 0.0f), xhi);
    y2 = fminf(fmaxf(y2, 0.0f), yhi);

    boxes[(size_t)b * N_PROP + r] = make_float4(x1, y1, x2, y2);  // a-major

    float s = scores[((size_t)b * A_N + a) * HW_N + hw];
    unsigned f = __float_as_uint(s);
    unsigned sk = f ^ ((f & 0x80000000u) ? 0xFFFFFFFFu : 0x80000000u);
    unsigned n_ref = (unsigned)(hw * A_N + a);
    unsigned long long key = ((unsigned long long)sk << 32) | (unsigned)(~n_ref);
    keys[(size_t)b * N_PROP + r] = key;
}

// ---------------------------------------------------------------------------
// Kernel B' (mid): LDS histogram from keys + findT + compact, one block per
// batch (only __syncthreads; no global ghist, no memset). Keys L2-hot.
// ---------------------------------------------------------------------------
__global__ __launch_bounds__(1024) void mid_kernel(
    const unsigned long long* __restrict__ keys,
    unsigned* __restrict__ cnt,
    unsigned long long* __restrict__ cand) {
    __shared__ unsigned hist[NBINS];
    __shared__ int Tlds;
    __shared__ unsigned cntL;
    const int b = blockIdx.x;
    const int tid = threadIdx.x;

    for (int i = tid; i < NBINS; i += 1024) hist[i] = 0u;
    if (tid == 0) cntL = 0u;
    __syncthreads();

    for (int it = 0; it < (N_PROP + 1023) / 1024; ++it) {
        int n = it * 1024 + tid;
        if (n < N_PROP) {
            unsigned long long k = keys[(size_t)b * N_PROP + n];
            atomicAdd(&hist[(unsigned)(k >> 52)], 1u);
        }
    }
    __syncthreads();

    // ---- findT (wave 0) ----
    if (tid < 64) {
        int lane = tid;
        unsigned gsum = 0;
        for (int j = 0; j < 64; ++j) gsum += hist[lane * 64 + j];
        unsigned s = gsum;
        for (int d = 1; d < 64; d <<= 1) {
            unsigned t = (unsigned)__shfl_down((int)s, d);
            if (lane + d < 64) s += t;
        }
        unsigned long long bal = __ballot(s >= PRE_NMS);
        int gstar = 63 - __builtin_clzll(bal);
        unsigned after = (gstar < 63)
            ? (unsigned)__builtin_amdgcn_readlane((int)s, gstar + 1) : 0u;
        unsigned R = PRE_NMS - after;
        unsigned s2 = hist[gstar * 64 + lane];
        for (int d = 1; d < 64; d <<= 1) {
            unsigned t = (unsigned)__shfl_down((int)s2, d);
            if (lane + d < 64) s2 += t;
        }
        unsigned long long bal2 = __ballot(s2 >= R);
        int j = 63 - __builtin_clzll(bal2);
        if (lane == 0) Tlds = gstar * 64 + j;
    }
    __syncthreads();

    // ---- compact (wave-aggregated LDS atomic) ----
    const int Tb = Tlds;
    for (int it = 0; it < (N_PROP + 1023) / 1024; ++it) {
        int n = it * 1024 + tid;
        bool pred = false;
        unsigned long long k = 0ull;
        if (n < N_PROP) {
            k = keys[(size_t)b * N_PROP + n];
            pred = ((int)(unsigned)(k >> 52) >= Tb);
        }
        unsigned long long m = __ballot(pred);
        if (m) {
            int lane = tid & 63;
            int lead = __ffsll((unsigned long long)m) - 1;
            unsigned base = 0;
            if (lane == lead) base = atomicAdd(&cntL, (unsigned)__popcll(m));
            base = __shfl((int)base, lead);
            if (pred) {
                unsigned pos = base + (unsigned)__popcll(m & ((1ull << lane) - 1ull));
                if (pos < CAND_MAX) cand[(size_t)b * CAND_MAX + pos] = k;
            }
        }
    }
    __syncthreads();
    if (tid == 0) cnt[b] = cntL;
}

// ---------------------------------------------------------------------------
// Kernel D: exact rank by pairwise count (unchanged from r8).
// ---------------------------------------------------------------------------
__global__ __launch_bounds__(256) void rank_scatter_kernel(
    const unsigned long long* __restrict__ cand,
    const unsigned* __restrict__ cnt,
    const float4* __restrict__ boxes,
    float4* __restrict__ sortedBoxes) {
    __shared__ unsigned long long sk[256];
    int b = blockIdx.y;
    int tid = threadIdx.x;
    int ci = blockIdx.x * 64 + (tid >> 2);
    int q = tid & 3;
    int mc = (int)min(cnt[b], (unsigned)CAND_MAX);
    unsigned long long my = (ci < mc) ? cand[(size_t)b * CAND_MAX + ci] : 0ull;
    int rank = 0;
    int nt = (mc + 255) >> 8;
    for (int t = 0; t < nt; ++t) {
        int j = t * 256 + tid;
        sk[tid] = (j < mc) ? cand[(size_t)b * CAND_MAX + j] : 0ull;
        __syncthreads();
#pragma unroll 16
        for (int c = 0; c < 64; ++c) {
            int cc = q * 64 + ((c + q * 17) & 63);  // stagger: avoid 4-way bank conflict
            rank += (sk[cc] > my) ? 1 : 0;
        }
        __syncthreads();
    }
    rank += __shfl_xor(rank, 1);
    rank += __shfl_xor(rank, 2);
    if (q == 0 && ci < mc && rank < PRE_NMS) {
        unsigned n_ref = ~(unsigned)(my & 0xFFFFFFFFull);
        unsigned a = n_ref % A_N;
        unsigned hw = n_ref / A_N;
        sortedBoxes[(size_t)b * SORT_N + rank] =
            boxes[(size_t)b * N_PROP + a * HW_N + hw];
    }
    if (q == 1) {
        int pi = blockIdx.x * 64 + (tid >> 2);
        if (pi >= PRE_NMS && pi < SORT_N)
            sortedBoxes[(size_t)b * SORT_N + pi] = make_float4(0.f, 0.f, 0.f, 0.f);
    }
}

// ---------------------------------------------------------------------------
// Kernel E: suppression bitmask, upper-triangle-only grid (unchanged from r8)
// ---------------------------------------------------------------------------
__global__ __launch_bounds__(256) void iou_mask_kernel(
    const float4* __restrict__ sortedBoxes,
    unsigned long long* __restrict__ colmaj,
    unsigned long long* __restrict__ rowmaj) {
#pragma clang fp contract(off)
    int b = blockIdx.y;
    int wv = threadIdx.x >> 6;
    int t = threadIdx.x & 63;
    int k = blockIdx.x * 4 + wv;          // 0..2079, upper-tri linear index
    int rc = 0;
    while (k >= 64 - rc) { k -= 64 - rc; ++rc; }
    int cc = rc + k;

    __shared__ float4 colb[4][64];
    colb[wv][t] = sortedBoxes[(size_t)b * SORT_N + cc * 64 + t];
    __syncthreads();

    int r = rc * 64 + t;
    float4 rb = sortedBoxes[(size_t)b * SORT_N + r];
    float rarea = (rb.z - rb.x) * (rb.w - rb.y);
    unsigned long long word = 0ull;
    for (int c = 0; c < 64; ++c) {
        int j = cc * 64 + c;
        float4 cb = colb[wv][c];
        float carea = (cb.z - cb.x) * (cb.w - cb.y);
        float ltx = fmaxf(rb.x, cb.x);
        float lty = fmaxf(rb.y, cb.y);
        float rbx = fminf(rb.z, cb.z);
        float rby = fminf(rb.w, cb.w);
        float iw = fmaxf(rbx - ltx, 0.0f);
        float ih = fmaxf(rby - lty, 0.0f);
        float inter = iw * ih;
        float iou = inter / (rarea + carea - inter + 1e-9f);
        if (iou > NMS_TH && j > r) word |= (1ull << c);
    }
    colmaj[((size_t)b * MASK_WORDS + cc) * SORT_N + r] = word;   // coalesced
    rowmaj[((size_t)b * SORT_N + r) * MASK_WORDS + cc] = word;   // scatter
}

// ---------------------------------------------------------------------------
// Kernel F: MULTI-WAVE greedy scan, RAW-BARRIER PIPELINED — r8 version
// VERBATIM (53.4us, proven r8/r9/r10). r11's per-kept readlane rewrite
// REGRESSED to 73.3us: the five redor64 reductions are INDEPENDENT 6-deep
// shuffle chains the compiler interleaves (~1 chain latency total), while
// the readlane loop was one fully-serial dependent chain. Reverted.
// ---------------------------------------------------------------------------
__device__ __forceinline__ unsigned long long rl64(unsigned long long v, int src) {
    unsigned lo = (unsigned)__builtin_amdgcn_readlane((int)(unsigned)(v & 0xFFFFFFFFull), src);
    unsigned hi = (unsigned)__builtin_amdgcn_readlane((int)(unsigned)(v >> 32), src);
    return ((unsigned long long)hi << 32) | lo;
}

__device__ __forceinline__ unsigned long long redor64(unsigned long long alive,
                                                      unsigned long long v, int lane) {
    unsigned long long x = ((alive >> lane) & 1ull) ? v : 0ull;
    x |= __shfl_xor(x, 1);
    x |= __shfl_xor(x, 2);
    x |= __shfl_xor(x, 4);
    x |= __shfl_xor(x, 8);
    x |= __shfl_xor(x, 16);
    x |= __shfl_xor(x, 32);
    return x;
}

__device__ __forceinline__ void block_sync() {
    asm volatile("s_waitcnt lgkmcnt(0)" ::: "memory");   // LDS visibility, NO vmcnt drain
    __builtin_amdgcn_s_barrier();
    asm volatile("" ::: "memory");
}

#define GLOAD(dst, addr) \
    asm volatile("global_load_dwordx2 %0, %1, off" : "=v"(dst) : "v"(addr))
#define WAITV0 asm volatile("s_waitcnt vmcnt(0)" ::: "memory")
#define SCHED0 __builtin_amdgcn_sched_barrier(0)

#define TILE_COL(P, t) ((t) < 6 ? 2 * (P) + (t) : 2 * (P) + 1 + ((t) - 6))
#define TILE_RB(P, t)  ((size_t)((t) < 6 ? 2 * (P) : 2 * (P) + 1) << 6)
#define TILE_ADDR(P, t) \
    (C + (size_t)(TILE_COL(P, t) < 64 ? TILE_COL(P, t) : 63) * SORT_N + TILE_RB(P, t) + lane)

#define ISSUE_PAIR(P)                                                          \
    do {                                                                       \
        pf_vmask = 0u;                                                         \
        GLOAD(pf0,  TILE_ADDR(P, 0));  if (TILE_COL(P, 0)  < 64) pf_vmask |= 1u << 0;  \
        GLOAD(pf1,  TILE_ADDR(P, 1));  if (TILE_COL(P, 1)  < 64) pf_vmask |= 1u << 1;  \
        GLOAD(pf2,  TILE_ADDR(P, 2));  if (TILE_COL(P, 2)  < 64) pf_vmask |= 1u << 2;  \
        GLOAD(pf3,  TILE_ADDR(P, 3));  if (TILE_COL(P, 3)  < 64) pf_vmask |= 1u << 3;  \
        GLOAD(pf4,  TILE_ADDR(P, 4));  if (TILE_COL(P, 4)  < 64) pf_vmask |= 1u << 4;  \
        GLOAD(pf5,  TILE_ADDR(P, 5));  if (TILE_COL(P, 5)  < 64) pf_vmask |= 1u << 5;  \
        GLOAD(pf6,  TILE_ADDR(P, 6));  if (TILE_COL(P, 6)  < 64) pf_vmask |= 1u << 6;  \
        GLOAD(pf7,  TILE_ADDR(P, 7));  if (TILE_COL(P, 7)  < 64) pf_vmask |= 1u << 7;  \
        GLOAD(pf8,  TILE_ADDR(P, 8));  if (TILE_COL(P, 8)  < 64) pf_vmask |= 1u << 8;  \
        GLOAD(pf9,  TILE_ADDR(P, 9));  if (TILE_COL(P, 9)  < 64) pf_vmask |= 1u << 9;  \
        GLOAD(pf10, TILE_ADDR(P, 10)); if (TILE_COL(P, 10) < 64) pf_vmask |= 1u << 10; \
    } while (0)

#define NEXTROW2(rk)                                                           \
    int rk;                                                                    \
    {                                                                          \
        if (xA) { int bb_ = __builtin_ctzll(xA); xA &= xA - 1; rk = baseA + bb_; } \
        else if (xB) { int bb_ = __builtin_ctzll(xB); xB &= xB - 1; rk = baseB + bb_; } \
        else rk = rpad;                                                        \
    }

__global__ __launch_bounds__(512, 1) void nms_scan_kernel(
    const unsigned long long* __restrict__ colmaj,
    const unsigned long long* __restrict__ rowmaj,
    const float4* __restrict__ sortedBoxes,
    float* __restrict__ out) {
    int b = blockIdx.x;
    int tid = threadIdx.x;
    int lane = tid & 63;
    int wv = tid >> 6;   // 0 decider, 1 prefetch, 2 helper, 3..7 loaders
    const unsigned long long* C = colmaj + (size_t)b * MASK_WORDS * SORT_N;
    const unsigned long long* R = rowmaj + (size_t)b * SORT_N * MASK_WORDS;

    __shared__ int kept[POST_NMS];
    __shared__ unsigned remW[MASK_WORDS][2];            // [word][lo,hi]
    __shared__ unsigned long long aliveLds[MASK_WORDS];
    __shared__ unsigned long long ring[4][11][64];      // tile ring, slot = pair&3
    __shared__ unsigned long long car2[2][2];           // helper d2 carries, slot = pair&1
    __shared__ int doneLds;
    __shared__ int kcntLds;

    if (tid < MASK_WORDS) { remW[tid][0] = 0u; remW[tid][1] = 0u; aliveLds[tid] = 0ull; }
    if (tid < 4) car2[tid >> 1][tid & 1] = 0ull;
    if (tid == 0) { doneLds = 0; kcntLds = 0; }

    unsigned long long pf0=0,pf1=0,pf2=0,pf3=0,pf4=0,pf5=0,pf6=0,pf7=0,pf8=0,pf9=0,pf10=0;
    unsigned pf_vmask = 0u;
    bool pf_have = false;
    unsigned long long gp0=0,gp1=0,gp2=0,gp3=0,gp4=0,gp5=0,gp6=0,gp7=0;
    bool ld_valid = false;

    // ---- prologue: stage pair 0 synchronously, issue pair 1 (in flight) ----
    if (wv == 1) {
        for (int t = 0; t < 11; ++t) {
            int col = TILE_COL(0, t);
            unsigned long long v =
                (col < 64) ? C[(size_t)col * SORT_N + TILE_RB(0, t) + lane] : 0ull;
            ring[0][t][lane] = v;
        }
        ISSUE_PAIR(1);
        pf_have = true;
    }
    block_sync();

    unsigned long long carA = 0ull, carB = 0ull;   // decider: d1 carries (pair q-1 -> q)
    int kcnt = 0;

    for (int q = 0; q < NPAIR; ++q) {
        if (wv == 0) {
            // ---------------- decider: pair q ----------------
            int A = 2 * q, Bg = A + 1, slot = q & 3;
            unsigned long long dA  = ring[slot][0][lane];
            unsigned long long tA1 = ring[slot][1][lane];
            unsigned long long tA2 = ring[slot][2][lane];
            unsigned long long tA3 = ring[slot][3][lane];
            unsigned long long dB  = ring[slot][6][lane];
            unsigned long long tB1 = ring[slot][7][lane];
            unsigned long long tB2 = ring[slot][8][lane];
            unsigned long long remA =
                ((unsigned long long)remW[A][1] << 32) | (unsigned long long)remW[A][0];
            unsigned long long remB =
                ((unsigned long long)remW[Bg][1] << 32) | (unsigned long long)remW[Bg][0];
            unsigned long long h2A = car2[q & 1][0];
            unsigned long long h2B = car2[q & 1][1];
            bool hit = false;
            unsigned long long aliveA = 0ull, aliveB = 0ull;
            unsigned long long pend = ~(remA | carA | h2A);
            while (pend) {
                int bit = __builtin_ctzll(pend);
                if (lane == 0) kept[kcnt] = (A << 6) + bit;
                ++kcnt;
                aliveA |= 1ull << bit;
                if (kcnt == POST_NMS) { hit = true; break; }
                pend &= ~(rl64(dA, bit) | (1ull << bit));
            }
            if (!hit) {
                unsigned long long nA1 = redor64(aliveA, tA1, lane);
                pend = ~(remB | carB | h2B | nA1);
                while (pend) {
                    int bit = __builtin_ctzll(pend);
                    if (lane == 0) kept[kcnt] = (Bg << 6) + bit;
                    ++kcnt;
                    aliveB |= 1ull << bit;
                    if (kcnt == POST_NMS) { hit = true; break; }
                    pend &= ~(rl64(dB, bit) | (1ull << bit));
                }
            }
            carA = redor64(aliveA, tA2, lane) | redor64(aliveB, tB1, lane);
            carB = redor64(aliveA, tA3, lane) | redor64(aliveB, tB2, lane);
            if (lane == 0) {
                aliveLds[A]  = aliveA;
                aliveLds[Bg] = aliveB;
                kcntLds = kcnt;
                if (hit) doneLds = 1;
            }
        } else if (wv == 1) {
            // ---------------- prefetch: write pair q+1, issue pair q+2 ------
            if (pf_have) {
                WAITV0;
                SCHED0;
                int wp = q + 1;
                if (wp < NPAIR) {
                    int ws = wp & 3;
                    ring[ws][0][lane]  = (pf_vmask & (1u << 0))  ? pf0  : 0ull;
                    ring[ws][1][lane]  = (pf_vmask & (1u << 1))  ? pf1  : 0ull;
                    ring[ws][2][lane]  = (pf_vmask & (1u << 2))  ? pf2  : 0ull;
                    ring[ws][3][lane]  = (pf_vmask & (1u << 3))  ? pf3  : 0ull;
                    ring[ws][4][lane]  = (pf_vmask & (1u << 4))  ? pf4  : 0ull;
                    ring[ws][5][lane]  = (pf_vmask & (1u << 5))  ? pf5  : 0ull;
                    ring[ws][6][lane]  = (pf_vmask & (1u << 6))  ? pf6  : 0ull;
                    ring[ws][7][lane]  = (pf_vmask & (1u << 7))  ? pf7  : 0ull;
                    ring[ws][8][lane]  = (pf_vmask & (1u << 8))  ? pf8  : 0ull;
                    ring[ws][9][lane]  = (pf_vmask & (1u << 9))  ? pf9  : 0ull;
                    ring[ws][10][lane] = (pf_vmask & (1u << 10)) ? pf10 : 0ull;
                }
                pf_have = false;
            }
            int ip = q + 2;
            if (ip < NPAIR) {
                ISSUE_PAIR(ip);
                pf_have = true;
            }
        } else if (wv == 2) {
            // ---------------- helper: pair p=q-1 d2 carries -> pair q+1 -----
            if (q >= 1) {
                int p = q - 1, sp = p & 3;
                unsigned long long aA = aliveLds[2 * p];
                unsigned long long aB = aliveLds[2 * p + 1];
                unsigned long long tA4 = ring[sp][4][lane];
                unsigned long long tA5 = ring[sp][5][lane];
                unsigned long long tB3 = ring[sp][9][lane];
                unsigned long long tB4 = ring[sp][10][lane];
                unsigned long long c0 = redor64(aA, tA4, lane) | redor64(aB, tB3, lane);
                unsigned long long c1 = redor64(aA, tA5, lane) | redor64(aB, tB4, lane);
                if (lane == 0) {
                    car2[(q + 1) & 1][0] = c0;
                    car2[(q + 1) & 1][1] = c1;
                }
            }
        } else {
            // ---------------- loaders: fold prev batch, issue pair q-1 ------
            if (ld_valid) {
                WAITV0;
                SCHED0;
                unsigned long long acc =
                    ((gp0 | gp1) | (gp2 | gp3)) | ((gp4 | gp5) | (gp6 | gp7));
                unsigned lo = (unsigned)acc, hi = (unsigned)(acc >> 32);
                if (lo) atomicOr(&remW[lane][0], lo);
                if (hi) atomicOr(&remW[lane][1], hi);
                ld_valid = false;
            }
            if (q >= 1) {
                int p = q - 1, gA = 2 * p, gB = 2 * p + 1;
                unsigned long long aA = aliveLds[gA];
                unsigned long long aB = aliveLds[gB];
                int k = wv - 3;                       // 0..NLW-1
                unsigned long long below = (1ull << lane) - 1ull;
                bool inA = (aA >> lane) & 1ull;
                bool inB = (aB >> lane) & 1ull;
                int posA = (int)__popcll(aA & below);
                int posB = (int)__popcll(aA) + (int)__popcll(aB & below);
                unsigned long long mA = __ballot(inA && (posA % NLW) == k);
                unsigned long long mB = __ballot(inB && (posB % NLW) == k);
                if (mA | mB) {
                    int baseA = gA << 6, baseB = gB << 6;
                    unsigned long long xA = mA, xB = mB;
                    int rpad = mA ? (baseA + __builtin_ctzll(mA))
                                  : (baseB + __builtin_ctzll(mB));
                    NEXTROW2(r0) NEXTROW2(r1) NEXTROW2(r2) NEXTROW2(r3)
                    NEXTROW2(r4) NEXTROW2(r5) NEXTROW2(r6) NEXTROW2(r7)
                    const unsigned long long* Rb = R + lane;
                    GLOAD(gp0, Rb + (size_t)r0 * MASK_WORDS);
                    GLOAD(gp1, Rb + (size_t)r1 * MASK_WORDS);
                    GLOAD(gp2, Rb + (size_t)r2 * MASK_WORDS);
                    GLOAD(gp3, Rb + (size_t)r3 * MASK_WORDS);
                    GLOAD(gp4, Rb + (size_t)r4 * MASK_WORDS);
                    GLOAD(gp5, Rb + (size_t)r5 * MASK_WORDS);
                    GLOAD(gp6, Rb + (size_t)r6 * MASK_WORDS);
                    GLOAD(gp7, Rb + (size_t)r7 * MASK_WORDS);
                    ld_valid = true;
                    // overflow rows (>8 for this wave): rare, serial
                    unsigned long long ovf = 0ull;
                    while (xA) {
                        int bb = __builtin_ctzll(xA); xA &= xA - 1;
                        ovf |= Rb[(size_t)(baseA + bb) * MASK_WORDS];
                    }
                    while (xB) {
                        int bb = __builtin_ctzll(xB); xB &= xB - 1;
                        ovf |= Rb[(size_t)(baseB + bb) * MASK_WORDS];
                    }
                    if (ovf) {
                        unsigned lo = (unsigned)ovf, hi = (unsigned)(ovf >> 32);
                        if (lo) atomicOr(&remW[lane][0], lo);
                        if (hi) atomicOr(&remW[lane][1], hi);
                    }
                }
            }
        }
        block_sync();
        if (doneLds) break;
    }

    WAITV0;             // drain any in-flight asm loads before ending
    __syncthreads();

    int kc = kcntLds;   // last write barrier-ordered before every exit path
    for (int r = tid; r < POST_NMS; r += 512) {
        float* o = out + ((size_t)b * POST_NMS + r) * 5;
        float4 bx = make_float4(0.f, 0.f, 0.f, 0.f);
        if (r < kc) bx = sortedBoxes[(size_t)b * SORT_N + kept[r]];
        o[0] = (float)b;
        o[1] = bx.x;
        o[2] = bx.y;
        o[3] = bx.z;
        o[4] = bx.w;
    }
}

// ---------------------------------------------------------------------------
extern "C" void kernel_launch(void* const* d_in, const int* in_sizes, int n_in,
                              void* d_out, int out_size, void* d_ws, size_t ws_size,
                              hipStream_t stream) {
    const float* scores  = (const float*)d_in[0];
    const float* deltas  = (const float*)d_in[1];
    const float* im_info = (const float*)d_in[2];
    const float* anchors = (const float*)d_in[3];
    float* out = (float*)d_out;

    char* ws = (char*)d_ws;
    size_t off = 0;
    float4* boxes = (float4*)(ws + off);
    off += (size_t)B_N * N_PROP * sizeof(float4);
    off = (off + 255) & ~(size_t)255;
    unsigned long long* keys = (unsigned long long*)(ws + off);
    off += (size_t)B_N * N_PROP * sizeof(unsigned long long);
    off = (off + 255) & ~(size_t)255;
    float4* sortedBoxes = (float4*)(ws + off);
    off += (size_t)B_N * SORT_N * sizeof(float4);
    off = (off + 255) & ~(size_t)255;
    unsigned long long* colmaj = (unsigned long long*)(ws + off);
    off += (size_t)B_N * MASK_WORDS * SORT_N * sizeof(unsigned long long);
    off = (off + 255) & ~(size_t)255;
    unsigned long long* rowmaj = (unsigned long long*)(ws + off);
    off += (size_t)B_N * SORT_N * MASK_WORDS * sizeof(unsigned long long);
    off = (off + 255) & ~(size_t)255;
    unsigned long long* cand = (unsigned long long*)(ws + off);
    off += (size_t)B_N * CAND_MAX * sizeof(unsigned long long);
    off = (off + 255) & ~(size_t)255;
    unsigned* cnt = (unsigned*)(ws + off);
    off += (size_t)B_N * sizeof(unsigned);

    decode_kernel<<<dim3(DEC_BLKS, B_N), 256, 0, stream>>>(
        scores, deltas, im_info, anchors, boxes, keys);
    mid_kernel<<<B_N, 1024, 0, stream>>>(keys, cnt, cand);
    rank_scatter_kernel<<<dim3(CAND_MAX / 64, B_N), 256, 0, stream>>>(
        cand, cnt, boxes, sortedBoxes);
    iou_mask_kernel<<<dim3(520, B_N), 256, 0, stream>>>(sortedBoxes, colmaj, rowmaj);
    nms_scan_kernel<<<B_N, 512, 0, stream>>>(colmaj, rowmaj, sortedBoxes, out);
}

// Round 13
// 199.117 us; speedup vs baseline: 1.1187x; 1.0222x over previous
//
#include <hip/hip_runtime.h>
#include <stdint.h>

#define A_N 9
#define H_N 50
#define W_N 76
#define HW_N (H_N * W_N)      // 3800
#define N_PROP (A_N * HW_N)   // 34200
#define B_N 4
#define PRE_NMS 4000
#define POST_NMS 300
#define NMS_TH 0.7f
#define SORT_N 4096
#define MASK_WORDS 64
#define CAND_MAX 5120
#define NBINS 4096
#define NPAIR 32
#define NLW 5
#define DEC_BLKS ((N_PROP + 255) / 256)   // 134

// ---------------------------------------------------------------------------
// Kernel A: decode + keys, WIDE grid (r10: narrow fused front was
// latency-bound on 4 CUs). No histogram — mid_kernel rebuilds from keys.
// ---------------------------------------------------------------------------
__global__ __launch_bounds__(256) void decode_kernel(
    const float* __restrict__ scores,
    const float* __restrict__ deltas,
    const float* __restrict__ im_info,
    const float* __restrict__ anchors,
    float4* __restrict__ boxes,
    unsigned long long* __restrict__ keys) {
#pragma clang fp contract(off)
    int tid = threadIdx.x;
    int b = blockIdx.y;
    int r = blockIdx.x * 256 + tid;
    if (r >= N_PROP) return;

    int a = r / HW_N;          // fixed across a wave
    int hw = r - a * HW_N;     // consecutive across lanes
    int hy = hw / W_N;
    int wx = hw - hy * W_N;

    float sx = (float)wx * 16.0f;
    float sy = (float)hy * 16.0f;
    float ax1 = anchors[a * 4 + 0] + sx;
    float ay1 = anchors[a * 4 + 1] + sy;
    float ax2 = anchors[a * 4 + 2] + sx;
    float ay2 = anchors[a * 4 + 3] + sy;
    float aw = ax2 - ax1 + 1.0f;
    float ah = ay2 - ay1 + 1.0f;
    float cx = ax1 + 0.5f * aw;
    float cy = ay1 + 0.5f * ah;

    const float* db = deltas + ((size_t)b * 36 + (size_t)a * 4) * HW_N + hw;
    float d0 = db[0];
    float d1 = db[HW_N];
    float d2 = db[2 * HW_N];
    float d3 = db[3 * HW_N];

    float pcx = d0 * aw + cx;
    float pcy = d1 * ah + cy;
    float pw  = expf(d2) * aw;
    float ph  = expf(d3) * ah;

    float x1 = pcx - 0.5f * pw;
    float y1 = pcy - 0.5f * ph;
    float x2 = pcx + 0.5f * pw;
    float y2 = pcy + 0.5f * ph;

    float xhi = im_info[b * 3 + 1] - 1.0f;
    float yhi = im_info[b * 3 + 0] - 1.0f;
    x1 = fminf(fmaxf(x1, 0.0f), xhi);
    y1 = fminf(fmaxf(y1, 0.0f), yhi);
    x2 = fminf(fmaxf(x2, 0.0f), xhi);
    y2 = fminf(fmaxf(y2, 0.0f), yhi);

    boxes[(size_t)b * N_PROP + r] = make_float4(x1, y1, x2, y2);  // a-major

    float s = scores[((size_t)b * A_N + a) * HW_N + hw];
    unsigned f = __float_as_uint(s);
    unsigned sk = f ^ ((f & 0x80000000u) ? 0xFFFFFFFFu : 0x80000000u);
    unsigned n_ref = (unsigned)(hw * A_N + a);
    unsigned long long key = ((unsigned long long)sk << 32) | (unsigned)(~n_ref);
    keys[(size_t)b * N_PROP + r] = key;
}

// ---------------------------------------------------------------------------
// Kernel B' (mid): LDS histogram from keys + findT + compact, one block per
// batch. NEW: 4 REPLICATED sub-histograms (waves 0-3/4-7/8-11/12-15 each own
// one) — scores are N(0,1) so ~50 hot bins; a single LDS hist serializes
// ~34200 atomics in the LDS pipe (~14us/batch at 4 CUs). Replication cuts
// same-address contention 4x; merge cost = 4 bins x 4 reads per thread.
// ---------------------------------------------------------------------------
__global__ __launch_bounds__(1024) void mid_kernel(
    const unsigned long long* __restrict__ keys,
    unsigned* __restrict__ cnt,
    unsigned long long* __restrict__ cand) {
    __shared__ unsigned hist[4 * NBINS];   // 64 KB
    __shared__ int Tlds;
    __shared__ unsigned cntL;
    const int b = blockIdx.x;
    const int tid = threadIdx.x;

    for (int i = tid; i < 4 * NBINS; i += 1024) hist[i] = 0u;
    if (tid == 0) cntL = 0u;
    __syncthreads();

    unsigned* myh = hist + ((tid >> 8) & 3) * NBINS;   // 4 waves per copy
    for (int it = 0; it < (N_PROP + 1023) / 1024; ++it) {
        int n = it * 1024 + tid;
        if (n < N_PROP) {
            unsigned long long k = keys[(size_t)b * N_PROP + n];
            atomicAdd(&myh[(unsigned)(k >> 52)], 1u);
        }
    }
    __syncthreads();
    // merge copies 1..3 into copy 0
    for (int i = tid; i < NBINS; i += 1024)
        hist[i] += hist[NBINS + i] + hist[2 * NBINS + i] + hist[3 * NBINS + i];
    __syncthreads();

    // ---- findT (wave 0) ----
    if (tid < 64) {
        int lane = tid;
        unsigned gsum = 0;
        for (int j = 0; j < 64; ++j) gsum += hist[lane * 64 + j];
        unsigned s = gsum;
        for (int d = 1; d < 64; d <<= 1) {
            unsigned t = (unsigned)__shfl_down((int)s, d);
            if (lane + d < 64) s += t;
        }
        unsigned long long bal = __ballot(s >= PRE_NMS);
        int gstar = 63 - __builtin_clzll(bal);
        unsigned after = (gstar < 63)
            ? (unsigned)__builtin_amdgcn_readlane((int)s, gstar + 1) : 0u;
        unsigned R = PRE_NMS - after;
        unsigned s2 = hist[gstar * 64 + lane];
        for (int d = 1; d < 64; d <<= 1) {
            unsigned t = (unsigned)__shfl_down((int)s2, d);
            if (lane + d < 64) s2 += t;
        }
        unsigned long long bal2 = __ballot(s2 >= R);
        int j = 63 - __builtin_clzll(bal2);
        if (lane == 0) Tlds = gstar * 64 + j;
    }
    __syncthreads();

    // ---- compact (wave-aggregated LDS atomic) ----
    const int Tb = Tlds;
    for (int it = 0; it < (N_PROP + 1023) / 1024; ++it) {
        int n = it * 1024 + tid;
        bool pred = false;
        unsigned long long k = 0ull;
        if (n < N_PROP) {
            k = keys[(size_t)b * N_PROP + n];
            pred = ((int)(unsigned)(k >> 52) >= Tb);
        }
        unsigned long long m = __ballot(pred);
        if (m) {
            int lane = tid & 63;
            int lead = __ffsll((unsigned long long)m) - 1;
            unsigned base = 0;
            if (lane == lead) base = atomicAdd(&cntL, (unsigned)__popcll(m));
            base = __shfl((int)base, lead);
            if (pred) {
                unsigned pos = base + (unsigned)__popcll(m & ((1ull << lane) - 1ull));
                if (pos < CAND_MAX) cand[(size_t)b * CAND_MAX + pos] = k;
            }
        }
    }
    __syncthreads();
    if (tid == 0) cnt[b] = cntL;
}

// ---------------------------------------------------------------------------
// Kernel D: exact rank by pairwise count (unchanged from r8).
// ---------------------------------------------------------------------------
__global__ __launch_bounds__(256) void rank_scatter_kernel(
    const unsigned long long* __restrict__ cand,
    const unsigned* __restrict__ cnt,
    const float4* __restrict__ boxes,
    float4* __restrict__ sortedBoxes) {
    __shared__ unsigned long long sk[256];
    int b = blockIdx.y;
    int tid = threadIdx.x;
    int ci = blockIdx.x * 64 + (tid >> 2);
    int q = tid & 3;
    int mc = (int)min(cnt[b], (unsigned)CAND_MAX);
    unsigned long long my = (ci < mc) ? cand[(size_t)b * CAND_MAX + ci] : 0ull;
    int rank = 0;
    int nt = (mc + 255) >> 8;
    for (int t = 0; t < nt; ++t) {
        int j = t * 256 + tid;
        sk[tid] = (j < mc) ? cand[(size_t)b * CAND_MAX + j] : 0ull;
        __syncthreads();
#pragma unroll 16
        for (int c = 0; c < 64; ++c) {
            int cc = q * 64 + ((c + q * 17) & 63);  // stagger: avoid 4-way bank conflict
            rank += (sk[cc] > my) ? 1 : 0;
        }
        __syncthreads();
    }
    rank += __shfl_xor(rank, 1);
    rank += __shfl_xor(rank, 2);
    if (q == 0 && ci < mc && rank < PRE_NMS) {
        unsigned n_ref = ~(unsigned)(my & 0xFFFFFFFFull);
        unsigned a = n_ref % A_N;
        unsigned hw = n_ref / A_N;
        sortedBoxes[(size_t)b * SORT_N + rank] =
            boxes[(size_t)b * N_PROP + a * HW_N + hw];
    }
    if (q == 1) {
        int pi = blockIdx.x * 64 + (tid >> 2);
        if (pi >= PRE_NMS && pi < SORT_N)
            sortedBoxes[(size_t)b * SORT_N + pi] = make_float4(0.f, 0.f, 0.f, 0.f);
    }
}

// ---------------------------------------------------------------------------
// Kernel E: suppression bitmask, upper-triangle-only grid (unchanged from r8)
// ---------------------------------------------------------------------------
__global__ __launch_bounds__(256) void iou_mask_kernel(
    const float4* __restrict__ sortedBoxes,
    unsigned long long* __restrict__ colmaj,
    unsigned long long* __restrict__ rowmaj) {
#pragma clang fp contract(off)
    int b = blockIdx.y;
    int wv = threadIdx.x >> 6;
    int t = threadIdx.x & 63;
    int k = blockIdx.x * 4 + wv;          // 0..2079, upper-tri linear index
    int rc = 0;
    while (k >= 64 - rc) { k -= 64 - rc; ++rc; }
    int cc = rc + k;

    __shared__ float4 colb[4][64];
    colb[wv][t] = sortedBoxes[(size_t)b * SORT_N + cc * 64 + t];
    __syncthreads();

    int r = rc * 64 + t;
    float4 rb = sortedBoxes[(size_t)b * SORT_N + r];
    float rarea = (rb.z - rb.x) * (rb.w - rb.y);
    unsigned long long word = 0ull;
    for (int c = 0; c < 64; ++c) {
        int j = cc * 64 + c;
        float4 cb = colb[wv][c];
        float carea = (cb.z - cb.x) * (cb.w - cb.y);
        float ltx = fmaxf(rb.x, cb.x);
        float lty = fmaxf(rb.y, cb.y);
        float rbx = fminf(rb.z, cb.z);
        float rby = fminf(rb.w, cb.w);
        float iw = fmaxf(rbx - ltx, 0.0f);
        float ih = fmaxf(rby - lty, 0.0f);
        float inter = iw * ih;
        float iou = inter / (rarea + carea - inter + 1e-9f);
        if (iou > NMS_TH && j > r) word |= (1ull << c);
    }
    colmaj[((size_t)b * MASK_WORDS + cc) * SORT_N + r] = word;   // coalesced
    rowmaj[((size_t)b * SORT_N + r) * MASK_WORDS + cc] = word;   // scatter
}

// ---------------------------------------------------------------------------
// Kernel F: MULTI-WAVE greedy scan, RAW-BARRIER PIPELINED (r8 structure).
// NEW: redor64 via DPP (update_dpp OR-chain: quad_perm xor1/xor2,
// row_half_mirror, row_mirror, bcast15, bcast31, readlane 63 — the canonical
// rocPRIM reduction). Pure VALU ~2cy/op vs __shfl_xor's ds_swizzle ~40-60cy
// x 6-deep x 2 words. nA1 + 4 carry reductions sit serially on the decider
// critical path; this cuts them ~6x. Chains/ordering untouched.
// ---------------------------------------------------------------------------
__device__ __forceinline__ unsigned long long rl64(unsigned long long v, int src) {
    unsigned lo = (unsigned)__builtin_amdgcn_readlane((int)(unsigned)(v & 0xFFFFFFFFull), src);
    unsigned hi = (unsigned)__builtin_amdgcn_readlane((int)(unsigned)(v >> 32), src);
    return ((unsigned long long)hi << 32) | lo;
}

__device__ __forceinline__ unsigned dpp_or32(unsigned x) {
    x |= (unsigned)__builtin_amdgcn_update_dpp(0, (int)x, 0xB1, 0xF, 0xF, true);  // quad_perm [1,0,3,2] = xor1
    x |= (unsigned)__builtin_amdgcn_update_dpp(0, (int)x, 0x4E, 0xF, 0xF, true);  // quad_perm [2,3,0,1] = xor2
    x |= (unsigned)__builtin_amdgcn_update_dpp(0, (int)x, 0x141, 0xF, 0xF, true); // row_half_mirror
    x |= (unsigned)__builtin_amdgcn_update_dpp(0, (int)x, 0x140, 0xF, 0xF, true); // row_mirror
    x |= (unsigned)__builtin_amdgcn_update_dpp(0, (int)x, 0x142, 0xF, 0xF, true); // row_bcast15
    x |= (unsigned)__builtin_amdgcn_update_dpp(0, (int)x, 0x143, 0xF, 0xF, true); // row_bcast31
    return (unsigned)__builtin_amdgcn_readlane((int)x, 63);                       // lane63 = full OR
}

__device__ __forceinline__ unsigned long long redor64(unsigned long long alive,
                                                      unsigned long long v, int lane) {
    unsigned long long x = ((alive >> lane) & 1ull) ? v : 0ull;
    unsigned lo = dpp_or32((unsigned)x);
    unsigned hi = dpp_or32((unsigned)(x >> 32));
    return ((unsigned long long)hi << 32) | lo;
}

__device__ __forceinline__ void block_sync() {
    asm volatile("s_waitcnt lgkmcnt(0)" ::: "memory");   // LDS visibility, NO vmcnt drain
    __builtin_amdgcn_s_barrier();
    asm volatile("" ::: "memory");
}

#define GLOAD(dst, addr) \
    asm volatile("global_load_dwordx2 %0, %1, off" : "=v"(dst) : "v"(addr))
#define WAITV0 asm volatile("s_waitcnt vmcnt(0)" ::: "memory")
#define SCHED0 __builtin_amdgcn_sched_barrier(0)

#define TILE_COL(P, t) ((t) < 6 ? 2 * (P) + (t) : 2 * (P) + 1 + ((t) - 6))
#define TILE_RB(P, t)  ((size_t)((t) < 6 ? 2 * (P) : 2 * (P) + 1) << 6)
#define TILE_ADDR(P, t) \
    (C + (size_t)(TILE_COL(P, t) < 64 ? TILE_COL(P, t) : 63) * SORT_N + TILE_RB(P, t) + lane)

#define ISSUE_PAIR(P)                                                          \
    do {                                                                       \
        pf_vmask = 0u;                                                         \
        GLOAD(pf0,  TILE_ADDR(P, 0));  if (TILE_COL(P, 0)  < 64) pf_vmask |= 1u << 0;  \
        GLOAD(pf1,  TILE_ADDR(P, 1));  if (TILE_COL(P, 1)  < 64) pf_vmask |= 1u << 1;  \
        GLOAD(pf2,  TILE_ADDR(P, 2));  if (TILE_COL(P, 2)  < 64) pf_vmask |= 1u << 2;  \
        GLOAD(pf3,  TILE_ADDR(P, 3));  if (TILE_COL(P, 3)  < 64) pf_vmask |= 1u << 3;  \
        GLOAD(pf4,  TILE_ADDR(P, 4));  if (TILE_COL(P, 4)  < 64) pf_vmask |= 1u << 4;  \
        GLOAD(pf5,  TILE_ADDR(P, 5));  if (TILE_COL(P, 5)  < 64) pf_vmask |= 1u << 5;  \
        GLOAD(pf6,  TILE_ADDR(P, 6));  if (TILE_COL(P, 6)  < 64) pf_vmask |= 1u << 6;  \
        GLOAD(pf7,  TILE_ADDR(P, 7));  if (TILE_COL(P, 7)  < 64) pf_vmask |= 1u << 7;  \
        GLOAD(pf8,  TILE_ADDR(P, 8));  if (TILE_COL(P, 8)  < 64) pf_vmask |= 1u << 8;  \
        GLOAD(pf9,  TILE_ADDR(P, 9));  if (TILE_COL(P, 9)  < 64) pf_vmask |= 1u << 9;  \
        GLOAD(pf10, TILE_ADDR(P, 10)); if (TILE_COL(P, 10) < 64) pf_vmask |= 1u << 10; \
    } while (0)

#define NEXTROW2(rk)                                                           \
    int rk;                                                                    \
    {                                                                          \
        if (xA) { int bb_ = __builtin_ctzll(xA); xA &= xA - 1; rk = baseA + bb_; } \
        else if (xB) { int bb_ = __builtin_ctzll(xB); xB &= xB - 1; rk = baseB + bb_; } \
        else rk = rpad;                                                        \
    }

__global__ __launch_bounds__(512, 1) void nms_scan_kernel(
    const unsigned long long* __restrict__ colmaj,
    const unsigned long long* __restrict__ rowmaj,
    const float4* __restrict__ sortedBoxes,
    float* __restrict__ out) {
    int b = blockIdx.x;
    int tid = threadIdx.x;
    int lane = tid & 63;
    int wv = tid >> 6;   // 0 decider, 1 prefetch, 2 helper, 3..7 loaders
    const unsigned long long* C = colmaj + (size_t)b * MASK_WORDS * SORT_N;
    const unsigned long long* R = rowmaj + (size_t)b * SORT_N * MASK_WORDS;

    __shared__ int kept[POST_NMS];
    __shared__ unsigned remW[MASK_WORDS][2];            // [word][lo,hi]
    __shared__ unsigned long long aliveLds[MASK_WORDS];
    __shared__ unsigned long long ring[4][11][64];      // tile ring, slot = pair&3
    __shared__ unsigned long long car2[2][2];           // helper d2 carries, slot = pair&1
    __shared__ int doneLds;
    __shared__ int kcntLds;

    if (tid < MASK_WORDS) { remW[tid][0] = 0u; remW[tid][1] = 0u; aliveLds[tid] = 0ull; }
    if (tid < 4) car2[tid >> 1][tid & 1] = 0ull;
    if (tid == 0) { doneLds = 0; kcntLds = 0; }

    unsigned long long pf0=0,pf1=0,pf2=0,pf3=0,pf4=0,pf5=0,pf6=0,pf7=0,pf8=0,pf9=0,pf10=0;
    unsigned pf_vmask = 0u;
    bool pf_have = false;
    unsigned long long gp0=0,gp1=0,gp2=0,gp3=0,gp4=0,gp5=0,gp6=0,gp7=0;
    bool ld_valid = false;

    // ---- prologue: stage pair 0 synchronously, issue pair 1 (in flight) ----
    if (wv == 1) {
        for (int t = 0; t < 11; ++t) {
            int col = TILE_COL(0, t);
            unsigned long long v =
                (col < 64) ? C[(size_t)col * SORT_N + TILE_RB(0, t) + lane] : 0ull;
            ring[0][t][lane] = v;
        }
        ISSUE_PAIR(1);
        pf_have = true;
    }
    block_sync();

    unsigned long long carA = 0ull, carB = 0ull;   // decider: d1 carries (pair q-1 -> q)
    int kcnt = 0;

    for (int q = 0; q < NPAIR; ++q) {
        if (wv == 0) {
            // ---------------- decider: pair q ----------------
            int A = 2 * q, Bg = A + 1, slot = q & 3;
            unsigned long long dA  = ring[slot][0][lane];
            unsigned long long tA1 = ring[slot][1][lane];
            unsigned long long tA2 = ring[slot][2][lane];
            unsigned long long tA3 = ring[slot][3][lane];
            unsigned long long dB  = ring[slot][6][lane];
            unsigned long long tB1 = ring[slot][7][lane];
            unsigned long long tB2 = ring[slot][8][lane];
            unsigned long long remA =
                ((unsigned long long)remW[A][1] << 32) | (unsigned long long)remW[A][0];
            unsigned long long remB =
                ((unsigned long long)remW[Bg][1] << 32) | (unsigned long long)remW[Bg][0];
            unsigned long long h2A = car2[q & 1][0];
            unsigned long long h2B = car2[q & 1][1];
            bool hit = false;
            unsigned long long aliveA = 0ull, aliveB = 0ull;
            unsigned long long pend = ~(remA | carA | h2A);
            while (pend) {
                int bit = __builtin_ctzll(pend);
                if (lane == 0) kept[kcnt] = (A << 6) + bit;
                ++kcnt;
                aliveA |= 1ull << bit;
                if (kcnt == POST_NMS) { hit = true; break; }
                pend &= ~(rl64(dA, bit) | (1ull << bit));
            }
            if (!hit) {
                unsigned long long nA1 = redor64(aliveA, tA1, lane);
                pend = ~(remB | carB | h2B | nA1);
                while (pend) {
                    int bit = __builtin_ctzll(pend);
                    if (lane == 0) kept[kcnt] = (Bg << 6) + bit;
                    ++kcnt;
                    aliveB |= 1ull << bit;
                    if (kcnt == POST_NMS) { hit = true; break; }
                    pend &= ~(rl64(dB, bit) | (1ull << bit));
                }
            }
            carA = redor64(aliveA, tA2, lane) | redor64(aliveB, tB1, lane);
            carB = redor64(aliveA, tA3, lane) | redor64(aliveB, tB2, lane);
            if (lane == 0) {
                aliveLds[A]  = aliveA;
                aliveLds[Bg] = aliveB;
                kcntLds = kcnt;
                if (hit) doneLds = 1;
            }
        } else if (wv == 1) {
            // ---------------- prefetch: write pair q+1, issue pair q+2 ------
            if (pf_have) {
                WAITV0;
                SCHED0;
                int wp = q + 1;
                if (wp < NPAIR) {
                    int ws = wp & 3;
                    ring[ws][0][lane]  = (pf_vmask & (1u << 0))  ? pf0  : 0ull;
                    ring[ws][1][lane]  = (pf_vmask & (1u << 1))  ? pf1  : 0ull;
                    ring[ws][2][lane]  = (pf_vmask & (1u << 2))  ? pf2  : 0ull;
                    ring[ws][3][lane]  = (pf_vmask & (1u << 3))  ? pf3  : 0ull;
                    ring[ws][4][lane]  = (pf_vmask & (1u << 4))  ? pf4  : 0ull;
                    ring[ws][5][lane]  = (pf_vmask & (1u << 5))  ? pf5  : 0ull;
                    ring[ws][6][lane]  = (pf_vmask & (1u << 6))  ? pf6  : 0ull;
                    ring[ws][7][lane]  = (pf_vmask & (1u << 7))  ? pf7  : 0ull;
                    ring[ws][8][lane]  = (pf_vmask & (1u << 8))  ? pf8  : 0ull;
                    ring[ws][9][lane]  = (pf_vmask & (1u << 9))  ? pf9  : 0ull;
                    ring[ws][10][lane] = (pf_vmask & (1u << 10)) ? pf10 : 0ull;
                }
                pf_have = false;
            }
            int ip = q + 2;
            if (ip < NPAIR) {
                ISSUE_PAIR(ip);
                pf_have = true;
            }
        } else if (wv == 2) {
            // ---------------- helper: pair p=q-1 d2 carries -> pair q+1 -----
            if (q >= 1) {
                int p = q - 1, sp = p & 3;
                unsigned long long aA = aliveLds[2 * p];
                unsigned long long aB = aliveLds[2 * p + 1];
                unsigned long long tA4 = ring[sp][4][lane];
                unsigned long long tA5 = ring[sp][5][lane];
                unsigned long long tB3 = ring[sp][9][lane];
                unsigned long long tB4 = ring[sp][10][lane];
                unsigned long long c0 = redor64(aA, tA4, lane) | redor64(aB, tB3, lane);
                unsigned long long c1 = redor64(aA, tA5, lane) | redor64(aB, tB4, lane);
                if (lane == 0) {
                    car2[(q + 1) & 1][0] = c0;
                    car2[(q + 1) & 1][1] = c1;
                }
            }
        } else {
            // ---------------- loaders: fold prev batch, issue pair q-1 ------
            if (ld_valid) {
                WAITV0;
                SCHED0;
                unsigned long long acc =
                    ((gp0 | gp1) | (gp2 | gp3)) | ((gp4 | gp5) | (gp6 | gp7));
                unsigned lo = (unsigned)acc, hi = (unsigned)(acc >> 32);
                if (lo) atomicOr(&remW[lane][0], lo);
                if (hi) atomicOr(&remW[lane][1], hi);
                ld_valid = false;
            }
            if (q >= 1) {
                int p = q - 1, gA = 2 * p, gB = 2 * p + 1;
                unsigned long long aA = aliveLds[gA];
                unsigned long long aB = aliveLds[gB];
                int k = wv - 3;                       // 0..NLW-1
                unsigned long long below = (1ull << lane) - 1ull;
                bool inA = (aA >> lane) & 1ull;
                bool inB = (aB >> lane) & 1ull;
                int posA = (int)__popcll(aA & below);
                int posB = (int)__popcll(aA) + (int)__popcll(aB & below);
                unsigned long long mA = __ballot(inA && (posA % NLW) == k);
                unsigned long long mB = __ballot(inB && (posB % NLW) == k);
                if (mA | mB) {
                    int baseA = gA << 6, baseB = gB << 6;
                    unsigned long long xA = mA, xB = mB;
                    int rpad = mA ? (baseA + __builtin_ctzll(mA))
                                  : (baseB + __builtin_ctzll(mB));
                    NEXTROW2(r0) NEXTROW2(r1) NEXTROW2(r2) NEXTROW2(r3)
                    NEXTROW2(r4) NEXTROW2(r5) NEXTROW2(r6) NEXTROW2(r7)
                    const unsigned long long* Rb = R + lane;
                    GLOAD(gp0, Rb + (size_t)r0 * MASK_WORDS);
                    GLOAD(gp1, Rb + (size_t)r1 * MASK_WORDS);
                    GLOAD(gp2, Rb + (size_t)r2 * MASK_WORDS);
                    GLOAD(gp3, Rb + (size_t)r3 * MASK_WORDS);
                    GLOAD(gp4, Rb + (size_t)r4 * MASK_WORDS);
                    GLOAD(gp5, Rb + (size_t)r5 * MASK_WORDS);
                    GLOAD(gp6, Rb + (size_t)r6 * MASK_WORDS);
                    GLOAD(gp7, Rb + (size_t)r7 * MASK_WORDS);
                    ld_valid = true;
                    // overflow rows (>8 for this wave): rare, serial
                    unsigned long long ovf = 0ull;
                    while (xA) {
                        int bb = __builtin_ctzll(xA); xA &= xA - 1;
                        ovf |= Rb[(size_t)(baseA + bb) * MASK_WORDS];
                    }
                    while (xB) {
                        int bb = __builtin_ctzll(xB); xB &= xB - 1;
                        ovf |= Rb[(size_t)(baseB + bb) * MASK_WORDS];
                    }
                    if (ovf) {
                        unsigned lo = (unsigned)ovf, hi = (unsigned)(ovf >> 32);
                        if (lo) atomicOr(&remW[lane][0], lo);
                        if (hi) atomicOr(&remW[lane][1], hi);
                    }
                }
            }
        }
        block_sync();
        if (doneLds) break;
    }

    WAITV0;             // drain any in-flight asm loads before ending
    __syncthreads();

    int kc = kcntLds;   // last write barrier-ordered before every exit path
    for (int r = tid; r < POST_NMS; r += 512) {
        float* o = out + ((size_t)b * POST_NMS + r) * 5;
        float4 bx = make_float4(0.f, 0.f, 0.f, 0.f);
        if (r < kc) bx = sortedBoxes[(size_t)b * SORT_N + kept[r]];
        o[0] = (float)b;
        o[1] = bx.x;
        o[2] = bx.y;
        o[3] = bx.z;
        o[4] = bx.w;
    }
}

// ---------------------------------------------------------------------------
extern "C" void kernel_launch(void* const* d_in, const int* in_sizes, int n_in,
                              void* d_out, int out_size, void* d_ws, size_t ws_size,
                              hipStream_t stream) {
    const float* scores  = (const float*)d_in[0];
    const float* deltas  = (const float*)d_in[1];
    const float* im_info = (const float*)d_in[2];
    const float* anchors = (const float*)d_in[3];
    float* out = (float*)d_out;

    char* ws = (char*)d_ws;
    size_t off = 0;
    float4* boxes = (float4*)(ws + off);
    off += (size_t)B_N * N_PROP * sizeof(float4);
    off = (off + 255) & ~(size_t)255;
    unsigned long long* keys = (unsigned long long*)(ws + off);
    off += (size_t)B_N * N_PROP * sizeof(unsigned long long);
    off = (off + 255) & ~(size_t)255;
    float4* sortedBoxes = (float4*)(ws + off);
    off += (size_t)B_N * SORT_N * sizeof(float4);
    off = (off + 255) & ~(size_t)255;
    unsigned long long* colmaj = (unsigned long long*)(ws + off);
    off += (size_t)B_N * MASK_WORDS * SORT_N * sizeof(unsigned long long);
    off = (off + 255) & ~(size_t)255;
    unsigned long long* rowmaj = (unsigned long long*)(ws + off);
    off += (size_t)B_N * SORT_N * MASK_WORDS * sizeof(unsigned long long);
    off = (off + 255) & ~(size_t)255;
    unsigned long long* cand = (unsigned long long*)(ws + off);
    off += (size_t)B_N * CAND_MAX * sizeof(unsigned long long);
    off = (off + 255) & ~(size_t)255;
    unsigned* cnt = (unsigned*)(ws + off);
    off += (size_t)B_N * sizeof(unsigned);

    decode_kernel<<<dim3(DEC_BLKS, B_N), 256, 0, stream>>>(
        scores, deltas, im_info, anchors, boxes, keys);
    mid_kernel<<<B_N, 1024, 0, stream>>>(keys, cnt, cand);
    rank_scatter_kernel<<<dim3(CAND_MAX / 64, B_N), 256, 0, stream>>>(
        cand, cnt, boxes, sortedBoxes);
    iou_mask_kernel<<<dim3(520, B_N), 256, 0, stream>>>(sortedBoxes, colmaj, rowmaj);
    nms_scan_kernel<<<B_N, 512, 0, stream>>>(colmaj, rowmaj, sortedBoxes, out);
}